// Round 1
// 234.959 us; speedup vs baseline: 1.0241x; 1.0241x over previous
//
#include <hip/hip_runtime.h>

// out = (x @ R^T) @ codes^T + bias, where codes = codebook[indices]
// x: [32,4096] f32, indices: [8192,4096] i32(0..15), codebook:[16] f32,
// R: [4096,4096] f32, bias: [8192] f32, out: [32,8192] f32.
//
// memset: y_ws = 0 (512 KB)
// K1: out = bias (prologue) ; y_ws += x @ R^T   (bf16 MFMA, ksplit 8, 4-chunk pipelined)
// K2: out += y @ codes^T                        (bf16 MFMA, ksplit 8, 4-chunk pipelined)
//
// R7: replace one-shot blocks (load->stall->mfma->atomics) with a 4-chunk
// register+LDS double-buffered pipeline: loads for chunk c+1 are issued BEFORE
// converting chunk c, so the HBM round-trip of each chunk overlaps the
// convert+barrier+MFMA of the previous one (counted-vmcnt, never drain-0).
// ksplit 16->8 in both kernels halves the contended f32 atomics (6.3M -> 3.1M).
//
// NOTE (R5 post-mortem): do NOT fuse K1/K2 with global-memory flags. The
// device-scope release/acquire fences required by cross-XCD non-coherence
// lower to L2 writeback/invalidate per block -> 750 us, HBM at 2% peak.

#define IN_F 4096
#define OUT_F 8192
#define BATCH 32
#define TSa 136   // LDS row stride in bf16 elems: 272 B = 17*16 B (16B-aligned rows, 4-bank rotation)

typedef short bf16x8s __attribute__((ext_vector_type(8)));   // 8 bf16 in 4 VGPRs
typedef float f32x4 __attribute__((ext_vector_type(4)));
typedef int   i32x4 __attribute__((ext_vector_type(4)));

// fp32 -> bf16 bits, round-to-nearest-even
__device__ __forceinline__ unsigned short f2bf(float f) {
    union { float f; unsigned int u; } v; v.f = f;
    unsigned int u = v.u;
    return (unsigned short)((u + 0x7fffu + ((u >> 16) & 1u)) >> 16);
}

// ---- staging helpers: tiles are [rows][128 cols], thread t owns rows r0+0,8,16.. col c4*4 ----
__device__ __forceinline__ void load8_nt(f32x4* dst, const float* base, int coff) {
    #pragma unroll
    for (int jj = 0; jj < 8; ++jj)
        dst[jj] = __builtin_nontemporal_load((const f32x4*)(base + (size_t)jj * 8 * IN_F + coff));
}
__device__ __forceinline__ void load8i_nt(i32x4* dst, const int* base, int coff) {
    #pragma unroll
    for (int jj = 0; jj < 8; ++jj)
        dst[jj] = __builtin_nontemporal_load((const i32x4*)(base + (size_t)jj * 8 * IN_F + coff));
}
__device__ __forceinline__ void load4(f32x4* dst, const float* base, int coff) {
    #pragma unroll
    for (int ii = 0; ii < 4; ++ii)
        dst[ii] = *(const f32x4*)(base + (size_t)ii * 8 * IN_F + coff);
}
__device__ __forceinline__ void cvt8(unsigned short* lds, int lb, const f32x4* v) {
    #pragma unroll
    for (int jj = 0; jj < 8; ++jj) {
        ushort4 pv;
        pv.x = f2bf(v[jj].x); pv.y = f2bf(v[jj].y);
        pv.z = f2bf(v[jj].z); pv.w = f2bf(v[jj].w);
        *(ushort4*)&lds[lb + jj * 8 * TSa] = pv;
    }
}
__device__ __forceinline__ void cvt4(unsigned short* lds, int lb, const f32x4* v) {
    #pragma unroll
    for (int ii = 0; ii < 4; ++ii) {
        ushort4 pv;
        pv.x = f2bf(v[ii].x); pv.y = f2bf(v[ii].y);
        pv.z = f2bf(v[ii].z); pv.w = f2bf(v[ii].w);
        *(ushort4*)&lds[lb + ii * 8 * TSa] = pv;
    }
}
__device__ __forceinline__ void cvt_codes(unsigned short* lds, int lb, const i32x4* v,
                                          const unsigned int* cbp) {
    #pragma unroll
    for (int jj = 0; jj < 8; ++jj) {
        unsigned int key0 = (unsigned int)v[jj].x | ((unsigned int)v[jj].y << 4);
        unsigned int key1 = (unsigned int)v[jj].z | ((unsigned int)v[jj].w << 4);
        uint2 pv; pv.x = cbp[key0]; pv.y = cbp[key1];
        *(uint2*)&lds[lb + jj * 8 * TSa] = pv;
    }
}
// 4 k-slices of 32 per chunk; acc0 = batch rows 0..15, acc1 = rows 16..31
__device__ __forceinline__ void mmstep(const unsigned short* B, const unsigned short* A,
                                       int bo, int ao, f32x4& acc0, f32x4& acc1) {
    #pragma unroll
    for (int ks = 0; ks < 4; ++ks) {
        bf16x8s bfr = *(const bf16x8s*)&B[bo + ks * 32];
        bf16x8s a0  = *(const bf16x8s*)&A[ao + ks * 32];
        bf16x8s a1  = *(const bf16x8s*)&A[ao + 16 * TSa + ks * 32];
        acc0 = __builtin_amdgcn_mfma_f32_16x16x32_bf16(a0, bfr, acc0, 0, 0, 0);
        acc1 = __builtin_amdgcn_mfma_f32_16x16x32_bf16(a1, bfr, acc1, 0, 0, 0);
    }
}

// ---------------- K1: y = x @ R^T ----------------
// grid = 64 j-tiles * 8 k-splits = 512 blocks, 256 threads (4 waves)
// each block: j-tile 64, k-range 512 processed as 4 pipelined chunks of 128
__global__ void __launch_bounds__(256, 3) k1_xRT(const float* __restrict__ x,
                                                 const float* __restrict__ R,
                                                 const float* __restrict__ bias,
                                                 float* __restrict__ out,
                                                 float* __restrict__ y_ws) {
    __shared__ unsigned short Bl[2][64 * TSa];  // R tile  [64 j][128 k] bf16, double-buffered
    __shared__ unsigned short Al[2][32 * TSa];  // x tile  [32 b][128 k] bf16, double-buffered

    const int tid  = threadIdx.x;
    const int jt   = blockIdx.x & 63;
    const int kq   = blockIdx.x >> 6;     // 0..7
    const int j0   = jt * 64;
    const int kb   = kq * 512;
    const int wave = tid >> 6, lane = tid & 63;
    const int n = lane & 15, quad = lane >> 4;
    const int r0 = tid >> 5, c4 = tid & 31;

    const float* rbase = R + (size_t)(j0 + r0) * IN_F + kb + c4 * 4;
    const float* xbase = x + (size_t)r0 * IN_F + kb + c4 * 4;
    const int lb = r0 * TSa + c4 * 4;
    const int bo = (wave * 16 + n) * TSa + quad * 8;
    const int ao = n * TSa + quad * 8;

    f32x4 rvA[8], rvB[8], xvA[4], xvB[4];
    load8_nt(rvA, rbase, 0);              // chunk 0 in flight
    load4(xvA, xbase, 0);

    {   // out = bias prologue: 262144 elems over 512 blocks = 2/thread (before K2's atomics)
        int e = (blockIdx.x * 256 + tid) * 2;
        float2 bv;
        bv.x = bias[e & (OUT_F - 1)];
        bv.y = bias[(e + 1) & (OUT_F - 1)];
        *(float2*)(out + e) = bv;
    }

    f32x4 acc0 = {0.f, 0.f, 0.f, 0.f};
    f32x4 acc1 = {0.f, 0.f, 0.f, 0.f};

    // pipelined chunks: issue c+1, convert c (stalls only on c's loads), barrier, MFMA c.
    // single barrier/chunk is race-free: writer of LDS[p] at chunk c is separated from
    // the previous reader of LDS[p] (mfma at c-2) by the c-1 barrier in program order.
    load8_nt(rvB, rbase, 128); load4(xvB, xbase, 128);
    cvt8(Bl[0], lb, rvA); cvt4(Al[0], lb, xvA);
    __syncthreads();
    mmstep(Bl[0], Al[0], bo, ao, acc0, acc1);

    load8_nt(rvA, rbase, 256); load4(xvA, xbase, 256);
    cvt8(Bl[1], lb, rvB); cvt4(Al[1], lb, xvB);
    __syncthreads();
    mmstep(Bl[1], Al[1], bo, ao, acc0, acc1);

    load8_nt(rvB, rbase, 384); load4(xvB, xbase, 384);
    cvt8(Bl[0], lb, rvA); cvt4(Al[0], lb, xvA);
    __syncthreads();
    mmstep(Bl[0], Al[0], bo, ao, acc0, acc1);

    cvt8(Bl[1], lb, rvB); cvt4(Al[1], lb, xvB);
    __syncthreads();
    mmstep(Bl[1], Al[1], bo, ao, acc0, acc1);

    // C/D layout: col=lane&15 (n), row=quad*4+r (m)
    const int jcol = j0 + wave * 16 + n;
    #pragma unroll
    for (int r = 0; r < 4; ++r) {
        int br = quad * 4 + r;
        atomicAdd(&y_ws[(size_t)br * IN_F + jcol], acc0[r]);
        atomicAdd(&y_ws[(size_t)(br + 16) * IN_F + jcol], acc1[r]);
    }
}

// ---------------- K2: out += y @ codes^T (fused dequant) ----------------
// grid = 128 o-tiles * 8 k-splits = 1024 blocks, 256 threads (4 waves)
// each block: o-tile 64, k-range 512 processed as 4 pipelined chunks of 128
__global__ void __launch_bounds__(256, 3) k2_out(const int* __restrict__ idx,
                                                 const float* __restrict__ cb,
                                                 const float* __restrict__ yws,
                                                 float* __restrict__ out) {
    __shared__ unsigned short Bl[2][64 * TSa];  // codes tile [64 o][128 k] bf16
    __shared__ unsigned short Al[2][32 * TSa];  // y tile     [32 b][128 k] bf16
    __shared__ unsigned int cbp[256];           // pair table: (i,j) -> bf16(cb[i]) | bf16(cb[j])<<16

    const int tid = threadIdx.x;
    const int ot = blockIdx.x & 127;
    const int kq = blockIdx.x >> 7;       // 0..7
    const int o0 = ot * 64;
    const int kb = kq * 512;
    const int wave = tid >> 6, lane = tid & 63;
    const int n = lane & 15, quad = lane >> 4;
    const int r0 = tid >> 5, c4 = tid & 31;

    const int*   ibase = idx + (size_t)(o0 + r0) * IN_F + kb + c4 * 4;
    const float* ybase = yws + (size_t)r0 * IN_F + kb + c4 * 4;
    const int lb = r0 * TSa + c4 * 4;
    const int bo = (wave * 16 + n) * TSa + quad * 8;
    const int ao = n * TSa + quad * 8;

    i32x4 ivA[8], ivB[8];
    f32x4 fvA[4], fvB[4];
    load8i_nt(ivA, ibase, 0);             // chunk 0 in flight
    load4(fvA, ybase, 0);
    {   // dequant pair table (overlaps the loads)
        unsigned int lo = f2bf(cb[tid & 15]);
        unsigned int hi = f2bf(cb[tid >> 4]);
        cbp[tid] = lo | (hi << 16);
    }
    load8i_nt(ivB, ibase, 128); load4(fvB, ybase, 128);   // chunk 1 in flight
    __syncthreads();   // cbp visible; chunk 0/1 loads still in flight

    f32x4 acc0 = {0.f, 0.f, 0.f, 0.f};
    f32x4 acc1 = {0.f, 0.f, 0.f, 0.f};

    cvt_codes(Bl[0], lb, ivA, cbp); cvt4(Al[0], lb, fvA);
    __syncthreads();
    mmstep(Bl[0], Al[0], bo, ao, acc0, acc1);

    load8i_nt(ivA, ibase, 256); load4(fvA, ybase, 256);
    cvt_codes(Bl[1], lb, ivB, cbp); cvt4(Al[1], lb, fvB);
    __syncthreads();
    mmstep(Bl[1], Al[1], bo, ao, acc0, acc1);

    load8i_nt(ivB, ibase, 384); load4(fvB, ybase, 384);
    cvt_codes(Bl[0], lb, ivA, cbp); cvt4(Al[0], lb, fvA);
    __syncthreads();
    mmstep(Bl[0], Al[0], bo, ao, acc0, acc1);

    cvt_codes(Bl[1], lb, ivB, cbp); cvt4(Al[1], lb, fvB);
    __syncthreads();
    mmstep(Bl[1], Al[1], bo, ao, acc0, acc1);

    const int ocol = o0 + wave * 16 + n;
    #pragma unroll
    for (int r = 0; r < 4; ++r) {
        int br = quad * 4 + r;
        atomicAdd(&out[(size_t)br * OUT_F + ocol], acc0[r]);
        atomicAdd(&out[(size_t)(br + 16) * OUT_F + ocol], acc1[r]);
    }
}

extern "C" void kernel_launch(void* const* d_in, const int* in_sizes, int n_in,
                              void* d_out, int out_size, void* d_ws, size_t ws_size,
                              hipStream_t stream) {
    (void)in_sizes; (void)n_in; (void)out_size; (void)ws_size;
    const float* x       = (const float*)d_in[0];
    const int*   indices = (const int*)d_in[1];
    const float* cb      = (const float*)d_in[2];
    const float* R       = (const float*)d_in[3];
    const float* bias    = (const float*)d_in[4];
    float* out  = (float*)d_out;
    float* y_ws = (float*)d_ws;           // 32*4096 f32 = 512 KB scratch

    hipMemsetAsync(y_ws, 0, (size_t)BATCH * IN_F * sizeof(float), stream);
    k1_xRT<<<dim3(512),  dim3(256), 0, stream>>>(x, R, bias, out, y_ws);
    k2_out<<<dim3(1024), dim3(256), 0, stream>>>(indices, cb, y_ws, out);
}